// Round 3
// baseline (664.869 us; speedup 1.0000x reference)
//
#include <hip/hip_runtime.h>
#include <math.h>

#define NN 20000
#define EE 640000
#define TILE 32                  // edges per wave; EE % TILE == 0 exactly
#define NWAVES (EE / TILE)       // 20000 waves, perfectly balanced
#define STEPS (TILE / 2)         // 16 steps; 2 edges per step (one per half-wave)

#define OUT_F4 (NN * 32)         // out is NN*128 floats = 640,000 float4
#define L_F4   (NN * 2)          // lsum is NN*8 floats  =  40,000 float4
#define Z_TOT  (OUT_F4 + L_F4)

// Zero the output accumulator and per-(node,head) softmax denominators.
__global__ __launch_bounds__(256)
void zero_accum(float4* __restrict__ out4, float4* __restrict__ l4) {
    int i = blockIdx.x * 256 + threadIdx.x;
    float4 z = make_float4(0.f, 0.f, 0.f, 0.f);
    if (i < OUT_F4) out4[i] = z;
    else if (i < Z_TOT) l4[i - OUT_F4] = z;
}

// Cross-lane add within the 4-lane head group, pure VALU (DPP quad_perm):
// no LDS pipe, no lgkmcnt wait. 0xB1 = [1,0,3,2] (xor 1), 0x4E = [2,3,0,1] (xor 2).
template<int CTRL>
__device__ __forceinline__ float dpp_add(float x) {
    int y = __builtin_amdgcn_mov_dpp(__float_as_int(x), CTRL, 0xF, 0xF, false);
    return x + __int_as_float(y);
}

// Edge-parallel segmented softmax-sum. One wave owns 32 consecutive sorted
// edges. Half-wave s processes edges t+s, t+s+2, ...; lane covers the float4
// feature quad at cl*4 (wave reads 1 KB contiguous per load instruction).
//
// Steady-state path is LDS-free: head-dot reduce via DPP, run boundaries via
// a per-tile ballot mask (bit i = dst[t+i] != dst[t+i-2], exactly "this
// half's run changed stepping from edge i-2 to i"). Softmax needs no max
// subtraction (shift-invariant, scores ~N(0,0.35)) so partial sums are
// order-independent and runs flush with device-scope atomicAdd.
__global__ __launch_bounds__(256)
void attn_edges(const float* __restrict__ key,   // (E,128)
                const float* __restrict__ q0,    // (N,32)
                const float* __restrict__ q1,    // (N,96)
                const float* __restrict__ val,   // (E,128)
                const int*   __restrict__ dst,   // (E,) sorted
                float*       __restrict__ out,   // [N*32 | N*96] accumulators
                float*       __restrict__ lsum)  // (N,8) denominators
{
    const int wid  = blockIdx.x * 4 + (threadIdx.x >> 6);
    const int lane = threadIdx.x & 63;
    const int s    = lane >> 5;
    const int cl   = lane & 31;
    const int t    = wid * TILE;

    // lane s*32+cl holds dst[t+cl] (both halves hold the same 32 values)
    const int dreg = dst[t + cl];

    // boundary mask: bit i (i>=2) of low 32 ballot bits = dst[t+i]!=dst[t+i-2]
    const int prev2 = __shfl(dreg, lane - 2);          // lanes 0,1: garbage, masked
    const unsigned long long bal = __ballot(dreg != prev2);
    const unsigned mask2  = (unsigned)bal & 0xFFFFFFFCu;
    const unsigned mybits = mask2 >> s;                // step j tests bit 2j

    const float* kp = key + (size_t)(t + s) * 128 + cl * 4;
    const float* vp = val + (size_t)(t + s) * 128 + cl * 4;
    const float scale = 0.08838834764831845f;          // 1/sqrt(128)

    int cur_n = __shfl(dreg, s * 33);                  // lane s*32+s: dst[t+s]
    float4 qv;
    qv.x = q0[cur_n * 32 + cl];
    qv.y = q1[cur_n * 96 + cl * 3 + 0];
    qv.z = q1[cur_n * 96 + cl * 3 + 1];
    qv.w = q1[cur_n * 96 + cl * 3 + 2];

    float  lrun = 0.f;
    float4 acc  = make_float4(0.f, 0.f, 0.f, 0.f);

    // depth-4 software pipeline, named buffers (compile-time indexing only)
    float4 kb0 = *(const float4*)(kp);        float4 vb0 = *(const float4*)(vp);
    float4 kb1 = *(const float4*)(kp + 256);  float4 vb1 = *(const float4*)(vp + 256);
    float4 kb2 = *(const float4*)(kp + 512);  float4 vb2 = *(const float4*)(vp + 512);
    float4 kb3 = *(const float4*)(kp + 768);  float4 vb3 = *(const float4*)(vp + 768);

#define STEP(J, KB, VB)                                                        \
    {                                                                          \
        const float4 kc = KB;                                                  \
        const float4 vc = VB;                                                  \
        if ((J) + 4 < STEPS) {                                                 \
            KB = *(const float4*)(kp + ((J) + 4) * 256);                       \
            VB = *(const float4*)(vp + ((J) + 4) * 256);                       \
        }                                                                      \
        if ((J) > 0 && (mybits & (1u << (2 * (J))))) {                         \
            /* flush finished run (condition uniform per half-wave) */         \
            atomicAdd(&out[cur_n * 32 + cl], acc.x);                           \
            float* o1 = out + NN * 32 + cur_n * 96 + cl * 3;                   \
            atomicAdd(o1 + 0, acc.y);                                          \
            atomicAdd(o1 + 1, acc.z);                                          \
            atomicAdd(o1 + 2, acc.w);                                          \
            if ((cl & 3) == 0) atomicAdd(&lsum[cur_n * 8 + (cl >> 2)], lrun);  \
            acc  = make_float4(0.f, 0.f, 0.f, 0.f);                            \
            lrun = 0.f;                                                        \
            cur_n = __shfl(dreg, (s << 5) + 2 * (J) + s);  /* own-half src */  \
            qv.x = q0[cur_n * 32 + cl];                                        \
            qv.y = q1[cur_n * 96 + cl * 3 + 0];                                \
            qv.z = q1[cur_n * 96 + cl * 3 + 1];                                \
            qv.w = q1[cur_n * 96 + cl * 3 + 2];                                \
        }                                                                      \
        float p = fmaf(kc.x, qv.x, fmaf(kc.y, qv.y, fmaf(kc.z, qv.z, kc.w * qv.w))); \
        p = dpp_add<0xB1>(p);                                                  \
        p = dpp_add<0x4E>(p);                                                  \
        const float w = __expf(p * scale);                                     \
        lrun += w;                                                             \
        acc.x = fmaf(w, vc.x, acc.x);                                          \
        acc.y = fmaf(w, vc.y, acc.y);                                          \
        acc.z = fmaf(w, vc.z, acc.z);                                          \
        acc.w = fmaf(w, vc.w, acc.w);                                          \
    }

    STEP(0,  kb0, vb0)
    STEP(1,  kb1, vb1)
    STEP(2,  kb2, vb2)
    STEP(3,  kb3, vb3)
    STEP(4,  kb0, vb0)
    STEP(5,  kb1, vb1)
    STEP(6,  kb2, vb2)
    STEP(7,  kb3, vb3)
    STEP(8,  kb0, vb0)
    STEP(9,  kb1, vb1)
    STEP(10, kb2, vb2)
    STEP(11, kb3, vb3)
    STEP(12, kb0, vb0)
    STEP(13, kb1, vb1)
    STEP(14, kb2, vb2)
    STEP(15, kb3, vb3)
#undef STEP

    // final flush
    atomicAdd(&out[cur_n * 32 + cl], acc.x);
    float* o1 = out + NN * 32 + cur_n * 96 + cl * 3;
    atomicAdd(o1 + 0, acc.y);
    atomicAdd(o1 + 1, acc.z);
    atomicAdd(o1 + 2, acc.w);
    if ((cl & 3) == 0) atomicAdd(&lsum[cur_n * 8 + (cl >> 2)], lrun);
}

// Divide accumulators by the per-(node,head) denominator.
__global__ __launch_bounds__(256)
void finalize(float* __restrict__ out, const float* __restrict__ lsum) {
    const int i = blockIdx.x * 256 + threadIdx.x;   // 0 .. NN*32-1
    const int n = i >> 5;
    const int c = i & 31;
    const float li = lsum[n * 8 + (c >> 2)];
    const float inv = (li > 0.f) ? 1.0f / li : 0.0f;  // deg==0 node -> zeros
    out[i] *= inv;
    float* o1 = out + NN * 32 + (size_t)n * 96 + c * 3;
    o1[0] *= inv;
    o1[1] *= inv;
    o1[2] *= inv;
}

extern "C" void kernel_launch(void* const* d_in, const int* in_sizes, int n_in,
                              void* d_out, int out_size, void* d_ws, size_t ws_size,
                              hipStream_t stream) {
    const float* key = (const float*)d_in[0];
    const float* q0  = (const float*)d_in[1];
    const float* q1  = (const float*)d_in[2];
    const float* val = (const float*)d_in[3];
    const int*   dst = (const int*)d_in[4];
    float* out  = (float*)d_out;
    float* lsum = (float*)d_ws;   // needs NN*8*4 = 640 KB of workspace

    zero_accum<<<(Z_TOT + 255) / 256, 256, 0, stream>>>((float4*)out, (float4*)lsum);
    attn_edges<<<NWAVES / 4, 256, 0, stream>>>(key, q0, q1, val, dst, out, lsum);
    finalize<<<(NN * 32) / 256, 256, 0, stream>>>(out, lsum);
}